// Round 1
// baseline (35866.702 us; speedup 1.0000x reference)
//
#include <hip/hip_runtime.h>
#include <hip/hip_bf16.h>

typedef unsigned int  uint32;
typedef unsigned short ushort16;
typedef float f32x2 __attribute__((ext_vector_type(2)));
typedef float f32x4 __attribute__((ext_vector_type(4)));
typedef short bf16x8 __attribute__((ext_vector_type(8)));

#define SEQN 8192
#define NBLK 32      // blocks per direction in the scan
#define UPB  16      // hidden units per block
// per-block weight slice: 64 gate rows x 512 k, bf16, LDS-resident

// ---------- helpers ----------
__device__ __forceinline__ uint32 bf16_rne(float f) {
    uint32 u = __float_as_uint(f);
    return (u + 0x7fffu + ((u >> 16) & 1u)) >> 16;
}
__device__ __forceinline__ uint32 pack_bf16x2(float a, float b) {
    return bf16_rne(a) | (bf16_rne(b) << 16);
}
__device__ __forceinline__ float bflo(uint32 u) { return __uint_as_float(u << 16); }
__device__ __forceinline__ float bfhi(uint32 u) { return __uint_as_float(u & 0xffff0000u); }
__device__ __forceinline__ float fsigmoid(float x) { return __fdividef(1.f, 1.f + __expf(-x)); }
__device__ __forceinline__ float ftanh_(float x) {
    float e = __expf(-2.f * fabsf(x));
    float r = __fdividef(1.f - e, 1.f + e);
    return copysignf(r, x);
}

// ---------- K0: fp32 -> bf16 conversions (+ scan-layout for w_hh) ----------
// sections (u32 pair outputs): embeds 3,145,728 | w_ih 2x786,432 | w_hh scan layout 2x524,288
__global__ __launch_bounds__(256) void convert_kernel(
    const float* __restrict__ embeds,
    const float* __restrict__ wihf, const float* __restrict__ wihb,
    const float* __restrict__ whhf, const float* __restrict__ whhb,
    uint32* __restrict__ emb16, uint32* __restrict__ wih16, uint32* __restrict__ whh16)
{
    int idx = blockIdx.x * 256 + threadIdx.x;
    if (idx < 3145728) {
        float2 v = ((const float2*)embeds)[idx];
        emb16[idx] = pack_bf16x2(v.x, v.y);
        return;
    }
    idx -= 3145728;
    if (idx < 1572864) {
        int d = idx / 786432;
        int p = idx - d * 786432;
        const float2* src = (const float2*)(d ? wihb : wihf);
        float2 v = src[p];
        wih16[idx] = pack_bf16x2(v.x, v.y);
        return;
    }
    idx -= 1572864;
    if (idx < 1048576) {
        int d    = idx >> 19;
        int rem  = idx & 524287;
        int blk  = rem >> 14;
        int rem2 = rem & 16383;
        int kblk = rem2 >> 8;
        int rem3 = rem2 & 255;
        int rr   = rem3 >> 2;
        int j4   = rem3 & 3;
        int grow = (rr >> 4) * 512 + blk * UPB + (rr & 15);
        int k0   = kblk * 8 + j4 * 2;
        const float* src = d ? whhb : whhf;
        float a = src[grow * 512 + k0];
        float b = src[grow * 512 + k0 + 1];
        whh16[idx] = pack_bf16x2(a, b);
    }
}

// ---------- K1: xg = embeds(bf16) @ w_ih^T + (b_ih + b_hh), output bf16 ----------
// MFMA 16x16x32 bf16. A-frag: m=lane&15, k=(lane>>4)*8+j ; B-frag: n=lane&15, k same.
// C/D: col=lane&15, row=(lane>>4)*4+reg.
__global__ __launch_bounds__(256) void gemm_xg_kernel(
    const ushort16* __restrict__ A,   // embeds bf16 [8192][768]
    const ushort16* __restrict__ W,   // w_ih bf16 [2048][768]
    const float* __restrict__ bih, const float* __restrict__ bhh,
    ushort16* __restrict__ xgout,     // [8192][2048] bf16
    int reverse)
{
    const int lane = threadIdx.x & 63;
    const int wv = threadIdx.x >> 6;
    const int n_base = blockIdx.x * 64;
    const int m0 = blockIdx.y * 64 + wv * 16;
    const int lm = lane & 15;
    const int kq = lane >> 4;

    f32x4 acc[4];
    #pragma unroll
    for (int i = 0; i < 4; ++i) acc[i] = (f32x4){0.f, 0.f, 0.f, 0.f};

    int m = m0 + lm;
    int arow = reverse ? (SEQN - 1 - m) : m;
    const ushort16* aptr = A + (size_t)arow * 768 + kq * 8;
    const ushort16* wptr = W + kq * 8;

    for (int kk = 0; kk < 768; kk += 32) {
        bf16x8 af = *(const bf16x8*)(aptr + kk);
        #pragma unroll
        for (int nt = 0; nt < 4; ++nt) {
            int n = n_base + nt * 16 + lm;
            bf16x8 bfv = *(const bf16x8*)(wptr + (size_t)n * 768 + kk);
            acc[nt] = __builtin_amdgcn_mfma_f32_16x16x32_bf16(af, bfv, acc[nt], 0, 0, 0);
        }
    }
    const int mrow0 = m0 + kq * 4;
    #pragma unroll
    for (int nt = 0; nt < 4; ++nt) {
        int n = n_base + nt * 16 + lm;
        float bias = bih[n] + bhh[n];
        #pragma unroll
        for (int rg = 0; rg < 4; ++rg) {
            float v = acc[nt][rg] + bias;
            xgout[(size_t)(mrow0 + rg) * 2048 + n] = (ushort16)bf16_rne(v);
        }
    }
}

// ---------- K2: the bidirectional LSTM scan ----------
// 64 blocks: dir = blockIdx.x>>5, blk = blockIdx.x&31. Each block owns 16 hidden
// units (64 gate rows). Weights bf16 in LDS [kblk(64)][row(64)][4xu32].
// Wave wv handles k-quarter wv, lane = row. Cross-block h exchange via hs[] +
// device-scope release/acquire + per-block flag (poisoned 0xAA.. = negative).
__global__ __launch_bounds__(256) void lstm_scan_kernel(
    const uint32* __restrict__ whh_scan,
    const ushort16* __restrict__ xg,
    float* __restrict__ hs,
    const float* __restrict__ h0, const float* __restrict__ c0,
    int* __restrict__ flags)
{
    __shared__ __align__(16) uint32 lds_w[16384];   // 64 KB
    __shared__ __align__(16) uint32 lds_h[256];     // 512 h as bf16 pairs
    __shared__ float lds_part[256];

    const int tid = threadIdx.x;
    const int dir = blockIdx.x >> 5;
    const int blk = blockIdx.x & 31;
    const int wv = tid >> 6;
    const int lane = tid & 63;

    const uint32* wsrc = whh_scan + (size_t)(dir * NBLK + blk) * 16384;
    for (int i = tid; i < 16384; i += 256) lds_w[i] = wsrc[i];

    const int grow = (lane >> 4) * 512 + blk * UPB + (lane & 15);  // gate row for r=lane
    const ushort16* xg_d = xg + (size_t)dir * SEQN * 2048;
    float* hs_d = hs + (size_t)dir * SEQN * 512;
    const float* h0_d = h0 + dir * 512;
    int* flg = flags + dir * NBLK;

    float c = 0.f;
    if (tid < UPB) c = c0[dir * 512 + blk * UPB + tid];

    __syncthreads();

    const uint4* wp_base = (const uint4*)lds_w + wv * 1024 + lane;  // (kblk*64+lane) uint4
    const uint4* hp_base = (const uint4*)lds_h + wv * 16;

    for (int t = 0; t < SEQN; ++t) {
        // prefetch this step's xg (independent of recurrence)
        float xgv = 0.f;
        if (wv == 0) {
            uint32 xv = xg_d[(size_t)t * 2048 + grow];
            xgv = bflo(xv);
        }
        if (t > 0) {
            if (wv == 0) {
                for (;;) {
                    int v = __hip_atomic_load(&flg[lane & (NBLK - 1)],
                                              __ATOMIC_RELAXED, __HIP_MEMORY_SCOPE_AGENT);
                    if (__all(v >= t)) break;
                }
            }
            __syncthreads();                                   // A
            __builtin_amdgcn_fence(__ATOMIC_ACQUIRE, "agent");
        }
        {
            int prow = dir ? (SEQN - t) : (t - 1);             // row of h_{t-1} in hs
            const float* hsrc = (t == 0) ? h0_d : (hs_d + (size_t)prow * 512);
            float2 hv = *(const float2*)(hsrc + tid * 2);
            lds_h[tid] = pack_bf16x2(hv.x, hv.y);
        }
        __syncthreads();                                       // B

        f32x2 acc2 = (f32x2){0.f, 0.f};
        #pragma unroll
        for (int i = 0; i < 16; ++i) {
            uint4 w4 = wp_base[i * 64];
            uint4 h4 = hp_base[i];
            { f32x2 a = {bflo(w4.x), bfhi(w4.x)}; f32x2 b = {bflo(h4.x), bfhi(h4.x)}; acc2 += a * b; }
            { f32x2 a = {bflo(w4.y), bfhi(w4.y)}; f32x2 b = {bflo(h4.y), bfhi(h4.y)}; acc2 += a * b; }
            { f32x2 a = {bflo(w4.z), bfhi(w4.z)}; f32x2 b = {bflo(h4.z), bfhi(h4.z)}; acc2 += a * b; }
            { f32x2 a = {bflo(w4.w), bfhi(w4.w)}; f32x2 b = {bflo(h4.w), bfhi(h4.w)}; acc2 += a * b; }
        }
        lds_part[tid] = acc2.x + acc2.y;
        __syncthreads();                                       // C

        if (wv == 0) {
            float gate = lds_part[lane] + lds_part[lane + 64]
                       + lds_part[lane + 128] + lds_part[lane + 192] + xgv;
            int u = lane & 15;
            float gi = __shfl(gate, u);
            float gf = __shfl(gate, 16 + u);
            float gg = __shfl(gate, 32 + u);
            float go = __shfl(gate, 48 + u);
            if (lane < UPB) {
                float iv = fsigmoid(gi), fvv = fsigmoid(gf);
                float gv = ftanh_(gg),   ov  = fsigmoid(go);
                c = fvv * c + iv * gv;
                float h = ov * ftanh_(c);
                int row_t = dir ? (SEQN - 1 - t) : t;
                hs_d[(size_t)row_t * 512 + blk * UPB + lane] = h;
            }
            __builtin_amdgcn_fence(__ATOMIC_RELEASE, "agent");
            if (lane == 0)
                __hip_atomic_store(&flg[blk], t + 1, __ATOMIC_RELAXED, __HIP_MEMORY_SCOPE_AGENT);
        }
    }
}

// ---------- K3: feats = concat(hs_f, hs_b) @ w_tag^T + b_tag ----------
__global__ __launch_bounds__(256) void feats_kernel(
    const float* __restrict__ hsf, const float* __restrict__ hsb,
    const float* __restrict__ wtag, const float* __restrict__ btag,
    float* __restrict__ feats)
{
    __shared__ float4 lh[4096];  // 16 rows x 1024 floats
    int t0 = blockIdx.x * 16;
    for (int i = threadIdx.x; i < 4096; i += 256) {
        int row = i >> 8, c4 = i & 255;
        float4 v;
        if (c4 < 128) v = ((const float4*)hsf)[(size_t)(t0 + row) * 128 + c4];
        else          v = ((const float4*)hsb)[(size_t)(t0 + row) * 128 + (c4 - 128)];
        lh[i] = v;
    }
    __syncthreads();
    if (threadIdx.x < 224) {
        int r = threadIdx.x / 14;
        int j = threadIdx.x - r * 14;
        const float4* wr = (const float4*)wtag + j * 256;
        float acc = btag[j];
        #pragma unroll 8
        for (int kk = 0; kk < 256; ++kk) {
            float4 h = lh[r * 256 + kk];
            float4 w = wr[kk];
            acc += h.x * w.x + h.y * w.y + h.z * w.z + h.w * w.w;
        }
        feats[(size_t)(t0 + r) * 14 + j] = acc;
    }
}

// ---------- K3b: gold score ----------
__global__ __launch_bounds__(256) void gold_kernel(
    const int* __restrict__ tags, const float* __restrict__ trans,
    const float* __restrict__ feats, float* __restrict__ gold)
{
    __shared__ float red[256];
    float s = 0.f;
    for (int t = threadIdx.x; t < SEQN; t += 256) {
        int tg = tags[t];
        int pv = (t == 0) ? 12 : tags[t - 1];
        s += trans[tg * 14 + pv] + feats[(size_t)t * 14 + tg];
    }
    red[threadIdx.x] = s;
    __syncthreads();
    for (int st = 128; st > 0; st >>= 1) {
        if (threadIdx.x < st) red[threadIdx.x] += red[threadIdx.x + st];
        __syncthreads();
    }
    if (threadIdx.x == 0) gold[0] = red[0] + trans[13 * 14 + tags[SEQN - 1]];
}

// ---------- K4: CRF forward (sequential, log2-domain, fv replicated per lane) ----------
__global__ __launch_bounds__(64) void crf_kernel(
    const float* __restrict__ feats, const float* __restrict__ trans,
    const float* __restrict__ gold, float* __restrict__ out)
{
    const int j = threadIdx.x;
    const float K2E = 1.4426950408889634f;
    float T2[14];
    #pragma unroll
    for (int i = 0; i < 14; ++i) T2[i] = (j < 14) ? trans[j * 14 + i] * K2E : 0.f;
    float fv[14];
    #pragma unroll
    for (int i = 0; i < 14; ++i) fv[i] = (i == 12) ? 0.f : -10000.f * K2E;
    float featq[16];
    #pragma unroll
    for (int d = 0; d < 16; ++d) featq[d] = (j < 14) ? feats[d * 14 + j] * K2E : 0.f;

    for (int tb = 0; tb < SEQN / 16; ++tb) {
        #pragma unroll
        for (int uu = 0; uu < 16; ++uu) {
            int t = tb * 16 + uu;
            float x[14];
            #pragma unroll
            for (int i = 0; i < 14; ++i) x[i] = fv[i] + T2[i];
            float m = x[0];
            #pragma unroll
            for (int i = 1; i < 14; ++i) m = fmaxf(m, x[i]);
            float s = 0.f;
            #pragma unroll
            for (int i = 0; i < 14; ++i) s += exp2f(x[i] - m);
            float nv = m + log2f(s) + featq[uu];
            #pragma unroll
            for (int i = 0; i < 14; ++i) fv[i] = __shfl(nv, i);
            int tn = t + 16;
            featq[uu] = (j < 14 && tn < SEQN) ? feats[(size_t)tn * 14 + j] * K2E : 0.f;
        }
    }
    if (j == 0) {
        float xx[14];
        #pragma unroll
        for (int i = 0; i < 14; ++i) xx[i] = fv[i] + trans[13 * 14 + i] * K2E;
        float m = xx[0];
        #pragma unroll
        for (int i = 1; i < 14; ++i) m = fmaxf(m, xx[i]);
        float s = 0.f;
        #pragma unroll
        for (int i = 0; i < 14; ++i) s += exp2f(xx[i] - m);
        float fwd = (m + log2f(s)) * 0.6931471805599453f;
        out[0] = fwd - gold[0];
    }
}

// ---------- host launch ----------
extern "C" void kernel_launch(void* const* d_in, const int* in_sizes, int n_in,
                              void* d_out, int out_size, void* d_ws, size_t ws_size,
                              hipStream_t stream) {
    const float* embeds = (const float*)d_in[0];
    const int*   tags   = (const int*)d_in[1];
    const float* wihf   = (const float*)d_in[2];
    const float* whhf   = (const float*)d_in[3];
    const float* bihf   = (const float*)d_in[4];
    const float* bhhf   = (const float*)d_in[5];
    const float* wihb   = (const float*)d_in[6];
    const float* whhb   = (const float*)d_in[7];
    const float* bihb   = (const float*)d_in[8];
    const float* bhhb   = (const float*)d_in[9];
    const float* wtag   = (const float*)d_in[10];
    const float* btag   = (const float*)d_in[11];
    const float* trans  = (const float*)d_in[12];
    const float* h0     = (const float*)d_in[13];
    const float* c0     = (const float*)d_in[14];

    char* ws = (char*)d_ws;
    uint32*   emb16 = (uint32*)(ws);                  // 12,582,912 B
    uint32*   wih16 = (uint32*)(ws + 12582912);       //  6,291,456 B
    uint32*   whh16 = (uint32*)(ws + 18874368);       //  4,194,304 B
    ushort16* xg    = (ushort16*)(ws + 23068672);     // 67,108,864 B
    float*    hs    = (float*)(ws + 90177536);        // 33,554,432 B
    float*    feats = (float*)(ws + 123731968);       //    458,752 B
    int*      flags = (int*)(ws + 124190720);         //        256 B
    float*    gold  = (float*)(ws + 124190976);       //          4 B

    convert_kernel<<<22528, 256, 0, stream>>>(embeds, wihf, wihb, whhf, whhb,
                                              emb16, wih16, whh16);
    gemm_xg_kernel<<<dim3(32, 128), 256, 0, stream>>>(
        (const ushort16*)emb16, (const ushort16*)wih16, bihf, bhhf, xg, 0);
    gemm_xg_kernel<<<dim3(32, 128), 256, 0, stream>>>(
        (const ushort16*)emb16, (const ushort16*)(wih16 + 786432), bihb, bhhb,
        xg + (size_t)SEQN * 2048, 1);
    lstm_scan_kernel<<<64, 256, 0, stream>>>(whh16, xg, hs, h0, c0, flags);
    feats_kernel<<<512, 256, 0, stream>>>(hs, hs + (size_t)SEQN * 512, wtag, btag, feats);
    gold_kernel<<<1, 256, 0, stream>>>(tags, trans, feats, gold);
    crf_kernel<<<1, 64, 0, stream>>>(feats, trans, gold, (float*)d_out);
}

// Round 2
// 21639.243 us; speedup vs baseline: 1.6575x; 1.6575x over previous
//
#include <hip/hip_runtime.h>
#include <hip/hip_bf16.h>

typedef unsigned int  uint32;
typedef unsigned short ushort16;
typedef float f32x2 __attribute__((ext_vector_type(2)));
typedef float f32x4 __attribute__((ext_vector_type(4)));
typedef short bf16x8 __attribute__((ext_vector_type(8)));

#define SEQN 8192
#define NBLK 32      // blocks per direction in the scan
#define UPB  16      // hidden units per block

// ---------- helpers ----------
__device__ __forceinline__ uint32 bf16_rne(float f) {
    uint32 u = __float_as_uint(f);
    return (u + 0x7fffu + ((u >> 16) & 1u)) >> 16;
}
__device__ __forceinline__ uint32 pack_bf16x2(float a, float b) {
    return bf16_rne(a) | (bf16_rne(b) << 16);
}
__device__ __forceinline__ float bflo(uint32 u) { return __uint_as_float(u << 16); }
__device__ __forceinline__ float bfhi(uint32 u) { return __uint_as_float(u & 0xffff0000u); }
__device__ __forceinline__ float bfus(ushort16 u) { return __uint_as_float(((uint32)u) << 16); }
__device__ __forceinline__ float fsigmoid(float x) { return __fdividef(1.f, 1.f + __expf(-x)); }
__device__ __forceinline__ float ftanh_(float x) {
    float e = __expf(-2.f * fabsf(x));
    float r = __fdividef(1.f - e, 1.f + e);
    return copysignf(r, x);
}

// ---------- K0: fp32 -> bf16 conversions (+ scan-layout for w_hh) ----------
__global__ __launch_bounds__(256) void convert_kernel(
    const float* __restrict__ embeds,
    const float* __restrict__ wihf, const float* __restrict__ wihb,
    const float* __restrict__ whhf, const float* __restrict__ whhb,
    uint32* __restrict__ emb16, uint32* __restrict__ wih16, uint32* __restrict__ whh16)
{
    int idx = blockIdx.x * 256 + threadIdx.x;
    if (idx < 3145728) {
        float2 v = ((const float2*)embeds)[idx];
        emb16[idx] = pack_bf16x2(v.x, v.y);
        return;
    }
    idx -= 3145728;
    if (idx < 1572864) {
        int d = idx / 786432;
        int p = idx - d * 786432;
        const float2* src = (const float2*)(d ? wihb : wihf);
        float2 v = src[p];
        wih16[idx] = pack_bf16x2(v.x, v.y);
        return;
    }
    idx -= 1572864;
    if (idx < 1048576) {
        int d    = idx >> 19;
        int rem  = idx & 524287;
        int blk  = rem >> 14;
        int rem2 = rem & 16383;
        int kblk = rem2 >> 8;
        int rem3 = rem2 & 255;
        int rr   = rem3 >> 2;
        int j4   = rem3 & 3;
        int grow = (rr >> 4) * 512 + blk * UPB + (rr & 15);
        int k0   = kblk * 8 + j4 * 2;
        const float* src = d ? whhb : whhf;
        float a = src[grow * 512 + k0];
        float b = src[grow * 512 + k0 + 1];
        whh16[idx] = pack_bf16x2(a, b);
    }
}

// ---------- K1: xg = embeds(bf16) @ w_ih^T + (b_ih + b_hh), output bf16 ----------
__global__ __launch_bounds__(256) void gemm_xg_kernel(
    const ushort16* __restrict__ A,   // embeds bf16 [8192][768]
    const ushort16* __restrict__ W,   // w_ih bf16 [2048][768]
    const float* __restrict__ bih, const float* __restrict__ bhh,
    ushort16* __restrict__ xgout,     // [8192][2048] bf16
    int reverse)
{
    const int lane = threadIdx.x & 63;
    const int wv = threadIdx.x >> 6;
    const int n_base = blockIdx.x * 64;
    const int m0 = blockIdx.y * 64 + wv * 16;
    const int lm = lane & 15;
    const int kq = lane >> 4;

    f32x4 acc[4];
    #pragma unroll
    for (int i = 0; i < 4; ++i) acc[i] = (f32x4){0.f, 0.f, 0.f, 0.f};

    int m = m0 + lm;
    int arow = reverse ? (SEQN - 1 - m) : m;
    const ushort16* aptr = A + (size_t)arow * 768 + kq * 8;
    const ushort16* wptr = W + kq * 8;

    for (int kk = 0; kk < 768; kk += 32) {
        bf16x8 af = *(const bf16x8*)(aptr + kk);
        #pragma unroll
        for (int nt = 0; nt < 4; ++nt) {
            int n = n_base + nt * 16 + lm;
            bf16x8 bfv = *(const bf16x8*)(wptr + (size_t)n * 768 + kk);
            acc[nt] = __builtin_amdgcn_mfma_f32_16x16x32_bf16(af, bfv, acc[nt], 0, 0, 0);
        }
    }
    const int mrow0 = m0 + kq * 4;
    #pragma unroll
    for (int nt = 0; nt < 4; ++nt) {
        int n = n_base + nt * 16 + lm;
        float bias = bih[n] + bhh[n];
        #pragma unroll
        for (int rg = 0; rg < 4; ++rg) {
            float v = acc[nt][rg] + bias;
            xgout[(size_t)(mrow0 + rg) * 2048 + n] = (ushort16)bf16_rne(v);
        }
    }
}

// ---------- K2: bidirectional LSTM scan, fence-free tag-in-word exchange ----------
// 64 blocks: dir = blockIdx.x>>5, blk = blockIdx.x&31. Each block owns 16 hidden
// units (64 gate rows), weight slice bf16 in LDS. Cross-block h exchange:
// xchg[dir][slot=t&1][unit] = (bf16(h)<<16) | (t+1)  via relaxed agent atomics
// (global_*_dword sc1: coherent at L3, NO cache-invalidating fences).
// Double-buffer safety: a block publishes h_{t+1} only after consuming all of
// h_t, and h_t[chunk B] exists only after B consumed all h_{t-1} => nobody can
// overwrite a value still being read. Tag makes data+validity atomic.
__global__ __launch_bounds__(256) void lstm_scan_kernel(
    const uint32* __restrict__ whh_scan,
    const ushort16* __restrict__ xg,
    float* __restrict__ hs,
    const float* __restrict__ h0, const float* __restrict__ c0,
    uint32* __restrict__ xchg)
{
    __shared__ __align__(16) uint32 lds_w[16384];   // 64 KB
    __shared__ __align__(16) uint32 lds_h[256];     // 512 h as bf16 pairs
    __shared__ float lds_part[256];

    const int tid = threadIdx.x;
    const int dir = blockIdx.x >> 5;
    const int blk = blockIdx.x & 31;
    const int wv = tid >> 6;
    const int lane = tid & 63;

    const uint32* wsrc = whh_scan + (size_t)(dir * NBLK + blk) * 16384;
    for (int i = tid; i < 16384; i += 256) lds_w[i] = wsrc[i];

    const int grow = (lane >> 4) * 512 + blk * UPB + (lane & 15);  // gate row
    const ushort16* xg_d = xg + (size_t)dir * SEQN * 2048;
    float* hs_d = hs + (size_t)dir * SEQN * 512;
    uint32* xb = xchg + dir * 1024;

    float c = 0.f;
    if (tid < UPB) c = c0[dir * 512 + blk * UPB + tid];

    // h_{-1} = h0 into LDS (bf16 pairs)
    {
        float2 hv = *(const float2*)(h0 + dir * 512 + tid * 2);
        lds_h[tid] = pack_bf16x2(hv.x, hv.y);
    }
    __syncthreads();

    const uint4* wp_base = (const uint4*)lds_w + wv * 1024 + lane;  // (kblk*64+lane)
    const uint4* hp_base = (const uint4*)lds_h + wv * 16;

    for (int t = 0; t < SEQN; ++t) {
        // xg for this step (only wave 0 needs it) — issue before anything else
        float xgv = 0.f;
        if (wv == 0) xgv = bfus(xg_d[(size_t)t * 2048 + grow]);

        if (t > 0) {
            // consume h_{t-1}: poll the two assigned exchange words until tag==t
            const uint32 tag = (uint32)t & 0xffffu;
            uint32* ps = xb + (((t - 1) & 1) << 9) + 2 * tid;
            uint32 a, b;
            for (;;) {
                a = __hip_atomic_load(ps,     __ATOMIC_RELAXED, __HIP_MEMORY_SCOPE_AGENT);
                b = __hip_atomic_load(ps + 1, __ATOMIC_RELAXED, __HIP_MEMORY_SCOPE_AGENT);
                if ((((a ^ tag) | (b ^ tag)) & 0xffffu) == 0u) break;
            }
            lds_h[tid] = (a >> 16) | (b & 0xffff0000u);
        }
        __syncthreads();                               // barrier 1: lds_h ready

        f32x2 acc2 = (f32x2){0.f, 0.f};
        #pragma unroll
        for (int i = 0; i < 16; ++i) {
            uint4 w4 = wp_base[i * 64];
            uint4 h4 = hp_base[i];
            { f32x2 a = {bflo(w4.x), bfhi(w4.x)}; f32x2 b = {bflo(h4.x), bfhi(h4.x)}; acc2 += a * b; }
            { f32x2 a = {bflo(w4.y), bfhi(w4.y)}; f32x2 b = {bflo(h4.y), bfhi(h4.y)}; acc2 += a * b; }
            { f32x2 a = {bflo(w4.z), bfhi(w4.z)}; f32x2 b = {bflo(h4.z), bfhi(h4.z)}; acc2 += a * b; }
            { f32x2 a = {bflo(w4.w), bfhi(w4.w)}; f32x2 b = {bflo(h4.w), bfhi(h4.w)}; acc2 += a * b; }
        }
        lds_part[tid] = acc2.x + acc2.y;
        __syncthreads();                               // barrier 2: partials ready, lds_h free

        if (wv == 0) {
            float gate = lds_part[lane] + lds_part[lane + 64]
                       + lds_part[lane + 128] + lds_part[lane + 192] + xgv;
            int u = lane & 15;
            float gi = __shfl(gate, u);
            float gf = __shfl(gate, 16 + u);
            float gg = __shfl(gate, 32 + u);
            float go = __shfl(gate, 48 + u);
            if (lane < UPB) {
                float iv = fsigmoid(gi), fvv = fsigmoid(gf);
                float gv = ftanh_(gg),   ov  = fsigmoid(go);
                c = fvv * c + iv * gv;
                float h = ov * ftanh_(c);
                int row_t = dir ? (SEQN - 1 - t) : t;
                hs_d[(size_t)row_t * 512 + blk * UPB + lane] = h;
                uint32 w = (bf16_rne(h) << 16) | ((uint32)(t + 1) & 0xffffu);
                __hip_atomic_store(xb + ((t & 1) << 9) + blk * UPB + lane, w,
                                   __ATOMIC_RELAXED, __HIP_MEMORY_SCOPE_AGENT);
            }
        }
        // waves 1-3 immediately poll the next step while wave 0 publishes
    }
}

// ---------- K3: feats = concat(hs_f, hs_b) @ w_tag^T + b_tag ----------
__global__ __launch_bounds__(256) void feats_kernel(
    const float* __restrict__ hsf, const float* __restrict__ hsb,
    const float* __restrict__ wtag, const float* __restrict__ btag,
    float* __restrict__ feats)
{
    __shared__ float4 lh[4096];  // 16 rows x 1024 floats
    int t0 = blockIdx.x * 16;
    for (int i = threadIdx.x; i < 4096; i += 256) {
        int row = i >> 8, c4 = i & 255;
        float4 v;
        if (c4 < 128) v = ((const float4*)hsf)[(size_t)(t0 + row) * 128 + c4];
        else          v = ((const float4*)hsb)[(size_t)(t0 + row) * 128 + (c4 - 128)];
        lh[i] = v;
    }
    __syncthreads();
    if (threadIdx.x < 224) {
        int r = threadIdx.x / 14;
        int j = threadIdx.x - r * 14;
        const float4* wr = (const float4*)wtag + j * 256;
        float acc = btag[j];
        #pragma unroll 8
        for (int kk = 0; kk < 256; ++kk) {
            float4 h = lh[r * 256 + kk];
            float4 w = wr[kk];
            acc += h.x * w.x + h.y * w.y + h.z * w.z + h.w * w.w;
        }
        feats[(size_t)(t0 + r) * 14 + j] = acc;
    }
}

// ---------- K3b: gold score ----------
__global__ __launch_bounds__(256) void gold_kernel(
    const int* __restrict__ tags, const float* __restrict__ trans,
    const float* __restrict__ feats, float* __restrict__ gold)
{
    __shared__ float red[256];
    float s = 0.f;
    for (int t = threadIdx.x; t < SEQN; t += 256) {
        int tg = tags[t];
        int pv = (t == 0) ? 12 : tags[t - 1];
        s += trans[tg * 14 + pv] + feats[(size_t)t * 14 + tg];
    }
    red[threadIdx.x] = s;
    __syncthreads();
    for (int st = 128; st > 0; st >>= 1) {
        if (threadIdx.x < st) red[threadIdx.x] += red[threadIdx.x + st];
        __syncthreads();
    }
    if (threadIdx.x == 0) gold[0] = red[0] + trans[13 * 14 + tags[SEQN - 1]];
}

// ---------- K4: CRF forward (sequential, log2-domain, fv replicated per lane) ----------
__global__ __launch_bounds__(64) void crf_kernel(
    const float* __restrict__ feats, const float* __restrict__ trans,
    const float* __restrict__ gold, float* __restrict__ out)
{
    const int j = threadIdx.x;
    const float K2E = 1.4426950408889634f;
    float T2[14];
    #pragma unroll
    for (int i = 0; i < 14; ++i) T2[i] = (j < 14) ? trans[j * 14 + i] * K2E : 0.f;
    float fv[14];
    #pragma unroll
    for (int i = 0; i < 14; ++i) fv[i] = (i == 12) ? 0.f : -10000.f * K2E;
    float featq[16];
    #pragma unroll
    for (int d = 0; d < 16; ++d) featq[d] = (j < 14) ? feats[d * 14 + j] * K2E : 0.f;

    for (int tb = 0; tb < SEQN / 16; ++tb) {
        #pragma unroll
        for (int uu = 0; uu < 16; ++uu) {
            int t = tb * 16 + uu;
            float x[14];
            #pragma unroll
            for (int i = 0; i < 14; ++i) x[i] = fv[i] + T2[i];
            float m = x[0];
            #pragma unroll
            for (int i = 1; i < 14; ++i) m = fmaxf(m, x[i]);
            float s = 0.f;
            #pragma unroll
            for (int i = 0; i < 14; ++i) s += exp2f(x[i] - m);
            float nv = m + log2f(s) + featq[uu];
            #pragma unroll
            for (int i = 0; i < 14; ++i) fv[i] = __shfl(nv, i);
            int tn = t + 16;
            featq[uu] = (j < 14 && tn < SEQN) ? feats[(size_t)tn * 14 + j] * K2E : 0.f;
        }
    }
    if (j == 0) {
        float xx[14];
        #pragma unroll
        for (int i = 0; i < 14; ++i) xx[i] = fv[i] + trans[13 * 14 + i] * K2E;
        float m = xx[0];
        #pragma unroll
        for (int i = 1; i < 14; ++i) m = fmaxf(m, xx[i]);
        float s = 0.f;
        #pragma unroll
        for (int i = 0; i < 14; ++i) s += exp2f(xx[i] - m);
        float fwd = (m + log2f(s)) * 0.6931471805599453f;
        out[0] = fwd - gold[0];
    }
}

// ---------- host launch ----------
extern "C" void kernel_launch(void* const* d_in, const int* in_sizes, int n_in,
                              void* d_out, int out_size, void* d_ws, size_t ws_size,
                              hipStream_t stream) {
    const float* embeds = (const float*)d_in[0];
    const int*   tags   = (const int*)d_in[1];
    const float* wihf   = (const float*)d_in[2];
    const float* whhf   = (const float*)d_in[3];
    const float* bihf   = (const float*)d_in[4];
    const float* bhhf   = (const float*)d_in[5];
    const float* wihb   = (const float*)d_in[6];
    const float* whhb   = (const float*)d_in[7];
    const float* bihb   = (const float*)d_in[8];
    const float* bhhb   = (const float*)d_in[9];
    const float* wtag   = (const float*)d_in[10];
    const float* btag   = (const float*)d_in[11];
    const float* trans  = (const float*)d_in[12];
    const float* h0     = (const float*)d_in[13];
    const float* c0     = (const float*)d_in[14];

    char* ws = (char*)d_ws;
    uint32*   emb16 = (uint32*)(ws);                  // 12,582,912 B
    uint32*   wih16 = (uint32*)(ws + 12582912);       //  6,291,456 B
    uint32*   whh16 = (uint32*)(ws + 18874368);       //  4,194,304 B
    ushort16* xg    = (ushort16*)(ws + 23068672);     // 67,108,864 B
    float*    hs    = (float*)(ws + 90177536);        // 33,554,432 B
    float*    feats = (float*)(ws + 123731968);       //    458,752 B
    uint32*   xchg  = (uint32*)(ws + 124190720);      //      8,192 B
    float*    gold  = (float*)(ws + 124198912);       //          4 B

    convert_kernel<<<22528, 256, 0, stream>>>(embeds, wihf, wihb, whhf, whhb,
                                              emb16, wih16, whh16);
    gemm_xg_kernel<<<dim3(32, 128), 256, 0, stream>>>(
        (const ushort16*)emb16, (const ushort16*)wih16, bihf, bhhf, xg, 0);
    gemm_xg_kernel<<<dim3(32, 128), 256, 0, stream>>>(
        (const ushort16*)emb16, (const ushort16*)(wih16 + 786432), bihb, bhhb,
        xg + (size_t)SEQN * 2048, 1);
    lstm_scan_kernel<<<64, 256, 0, stream>>>(whh16, xg, hs, h0, c0, xchg);
    feats_kernel<<<512, 256, 0, stream>>>(hs, hs + (size_t)SEQN * 512, wtag, btag, feats);
    gold_kernel<<<1, 256, 0, stream>>>(tags, trans, feats, gold);
    crf_kernel<<<1, 64, 0, stream>>>(feats, trans, gold, (float*)d_out);
}

// Round 3
// 13843.375 us; speedup vs baseline: 2.5909x; 1.5631x over previous
//
#include <hip/hip_runtime.h>
#include <hip/hip_bf16.h>

typedef unsigned int  uint32;
typedef unsigned short ushort16;
typedef float f32x2 __attribute__((ext_vector_type(2)));
typedef float f32x4 __attribute__((ext_vector_type(4)));
typedef short bf16x8 __attribute__((ext_vector_type(8)));

#define SEQN 8192
#define NBLK 32      // blocks per direction in the scan
#define UPB  16      // hidden units per block
#define K2E  1.4426950408889634f
#define LN2  0.6931471805599453f

#if __has_builtin(__builtin_amdgcn_exp2f)
#define EXP2F __builtin_amdgcn_exp2f
#else
#define EXP2F exp2f
#endif
#if __has_builtin(__builtin_amdgcn_logf)
#define LOG2F __builtin_amdgcn_logf
#else
#define LOG2F log2f
#endif
#if __has_builtin(__builtin_amdgcn_rcpf)
#define RCPF  __builtin_amdgcn_rcpf
#else
#define RCPF(x) (1.0f/(x))
#endif

// ---------- helpers ----------
__device__ __forceinline__ uint32 bf16_rne(float f) {
    uint32 u = __float_as_uint(f);
    return (u + 0x7fffu + ((u >> 16) & 1u)) >> 16;
}
__device__ __forceinline__ uint32 pack_bf16x2(float a, float b) {
    return bf16_rne(a) | (bf16_rne(b) << 16);
}
__device__ __forceinline__ float bfus(ushort16 u) { return __uint_as_float(((uint32)u) << 16); }
// fast sigmoid/tanh via exp2+rcp (epilogue is on the scan critical path)
__device__ __forceinline__ float fsigmoid(float x) {
    return RCPF(1.f + EXP2F(-K2E * x));
}
__device__ __forceinline__ float ftanh_(float x) {
    float e = EXP2F(-2.f * K2E * fabsf(x));
    float r = (1.f - e) * RCPF(1.f + e);
    return copysignf(r, x);
}

// ---------- K0: fp32 -> bf16 conversions ----------
// emb16: [8192][768] pairs; wih16: 2x[2048][768] pairs;
// whh16: A-fragment scan layout, uint4 idx = ((dir*32+blk)*64 + wv*16 + i)*64 + lane
//   lane: m=lane&15 (unit), kq=lane>>4; grow = wv*512 + blk*16 + m; k = i*32+kq*8+2w(+1)
__global__ __launch_bounds__(256) void convert_kernel(
    const float* __restrict__ embeds,
    const float* __restrict__ wihf, const float* __restrict__ wihb,
    const float* __restrict__ whhf, const float* __restrict__ whhb,
    uint32* __restrict__ emb16, uint32* __restrict__ wih16, uint32* __restrict__ whh16)
{
    int idx = blockIdx.x * 256 + threadIdx.x;
    if (idx < 3145728) {
        float2 v = ((const float2*)embeds)[idx];
        emb16[idx] = pack_bf16x2(v.x, v.y);
        return;
    }
    idx -= 3145728;
    if (idx < 1572864) {
        int d = idx / 786432;
        int p = idx - d * 786432;
        const float2* src = (const float2*)(d ? wihb : wihf);
        float2 v = src[p];
        wih16[idx] = pack_bf16x2(v.x, v.y);
        return;
    }
    idx -= 1572864;
    if (idx < 1048576) {
        int d    = idx >> 19;
        int rem  = idx & 524287;
        int blk  = rem >> 14;
        int s    = rem & 16383;
        int w    = s & 3;
        int q4   = s >> 2;
        int lane = q4 & 63;
        int i    = (q4 >> 6) & 15;
        int wv   = (q4 >> 10) & 3;
        int m    = lane & 15;
        int kq   = lane >> 4;
        int grow = wv * 512 + blk * 16 + m;
        int k0   = i * 32 + kq * 8 + 2 * w;
        const float* src = d ? whhb : whhf;
        whh16[idx] = pack_bf16x2(src[grow * 512 + k0], src[grow * 512 + k0 + 1]);
    }
}

// ---------- K1: xg = embeds(bf16) @ w_ih^T + (b_ih + b_hh), bf16 out in scan layout ----------
// xg layout: [t][blk2(32)][r(64)] where r = g*16 + (unit&15), blk2 = unit>>4
__global__ __launch_bounds__(256) void gemm_xg_kernel(
    const ushort16* __restrict__ A,   // embeds bf16 [8192][768]
    const ushort16* __restrict__ W,   // w_ih bf16 [2048][768]
    const float* __restrict__ bih, const float* __restrict__ bhh,
    ushort16* __restrict__ xgout,     // [8192][2048] bf16, scan layout
    int reverse)
{
    const int lane = threadIdx.x & 63;
    const int wv = threadIdx.x >> 6;
    const int n_base = blockIdx.x * 64;
    const int m0 = blockIdx.y * 64 + wv * 16;
    const int lm = lane & 15;
    const int kq = lane >> 4;

    f32x4 acc[4];
    #pragma unroll
    for (int i = 0; i < 4; ++i) acc[i] = (f32x4){0.f, 0.f, 0.f, 0.f};

    int m = m0 + lm;
    int arow = reverse ? (SEQN - 1 - m) : m;
    const ushort16* aptr = A + (size_t)arow * 768 + kq * 8;
    const ushort16* wptr = W + kq * 8;

    for (int kk = 0; kk < 768; kk += 32) {
        bf16x8 af = *(const bf16x8*)(aptr + kk);
        #pragma unroll
        for (int nt = 0; nt < 4; ++nt) {
            int n = n_base + nt * 16 + lm;
            bf16x8 bfv = *(const bf16x8*)(wptr + (size_t)n * 768 + kk);
            acc[nt] = __builtin_amdgcn_mfma_f32_16x16x32_bf16(af, bfv, acc[nt], 0, 0, 0);
        }
    }
    const int mrow0 = m0 + kq * 4;
    #pragma unroll
    for (int nt = 0; nt < 4; ++nt) {
        int n = n_base + nt * 16 + lm;
        float bias = bih[n] + bhh[n];
        int blk2 = (n >> 4) & 31;
        int r    = ((n >> 9) << 4) | (n & 15);
        #pragma unroll
        for (int rg = 0; rg < 4; ++rg) {
            float v = acc[nt][rg] + bias;
            xgout[(size_t)(mrow0 + rg) * 2048 + blk2 * 64 + r] = (ushort16)bf16_rne(v);
        }
    }
}

// ---------- K2: bidirectional LSTM scan — weights in VGPRs, matvec via MFMA ----------
// 64 blocks: dir=blockIdx.x>>5, blk=blockIdx.x&31; 16 units (64 gate rows)/block.
// Wave wv owns gate-type wv: A-frags (16 ktiles x 4 VGPRs) preloaded to registers.
// B operand: h in column n=0 only (lanes 0,16,32,48 carry 8 bf16 each from LDS).
// Exchange: tag-in-word relaxed agent atomics (round-2 scheme, fence-free).
__global__ __launch_bounds__(256) void lstm_scan_kernel(
    const uint4* __restrict__ whh_scan,
    const ushort16* __restrict__ xg,
    float* __restrict__ hs,
    const float* __restrict__ h0, const float* __restrict__ c0,
    uint32* __restrict__ xchg)
{
    __shared__ __align__(16) uint32 lds_h[256];     // 512 h as bf16 pairs
    __shared__ __align__(16) float lds_gates[64];   // [g*16+u]

    const int tid = threadIdx.x;
    const int dir = blockIdx.x >> 5;
    const int blk = blockIdx.x & 31;
    const int wv = tid >> 6;
    const int lane = tid & 63;
    const int kq = lane >> 4;
    const bool bfl = (lane & 15) == 0;

    // preload weight A-fragments into VGPRs (64 VGPRs)
    uint4 wreg[16];
    const uint4* wsl = whh_scan + (size_t)(dir * 32 + blk) * 4096 + (wv * 16) * 64 + lane;
    #pragma unroll
    for (int i = 0; i < 16; ++i) wreg[i] = wsl[i * 64];

    const ushort16* xg_d = xg + (size_t)dir * SEQN * 2048;
    float* hs_d = hs + (size_t)dir * SEQN * 512;
    uint32* xb = xchg + dir * 1024;

    float c = 0.f;
    if (tid < UPB) c = c0[dir * 512 + blk * UPB + tid];
    {
        float2 hv = *(const float2*)(h0 + dir * 512 + tid * 2);
        lds_h[tid] = pack_bf16x2(hv.x, hv.y);
    }
    __syncthreads();

    const uint4* lh4 = (const uint4*)lds_h;

    for (int t = 0; t < SEQN; ++t) {
        float xgv = 0.f;
        if (wv == 0) xgv = bfus(xg_d[(size_t)t * 2048 + blk * 64 + lane]);

        if (t > 0) {
            const uint32 tag = (uint32)t & 0xffffu;
            uint32* ps = xb + (((t - 1) & 1) << 9) + 2 * tid;
            uint32 a, b;
            for (;;) {
                a = __hip_atomic_load(ps,     __ATOMIC_RELAXED, __HIP_MEMORY_SCOPE_AGENT);
                b = __hip_atomic_load(ps + 1, __ATOMIC_RELAXED, __HIP_MEMORY_SCOPE_AGENT);
                if ((((a ^ tag) | (b ^ tag)) & 0xffffu) == 0u) break;
            }
            lds_h[tid] = (a >> 16) | (b & 0xffff0000u);
        }
        __syncthreads();                               // barrier 1: lds_h ready

        f32x4 acc0 = (f32x4){0.f, 0.f, 0.f, 0.f};
        f32x4 acc1 = (f32x4){0.f, 0.f, 0.f, 0.f};
        #pragma unroll
        for (int i = 0; i < 16; i += 2) {
            uint4 h4a = (uint4){0, 0, 0, 0}, h4b = (uint4){0, 0, 0, 0};
            if (bfl) {
                h4a = lh4[i * 4 + kq];
                h4b = lh4[(i + 1) * 4 + kq];
            }
            acc0 = __builtin_amdgcn_mfma_f32_16x16x32_bf16(
                *(const bf16x8*)&wreg[i],     *(const bf16x8*)&h4a, acc0, 0, 0, 0);
            acc1 = __builtin_amdgcn_mfma_f32_16x16x32_bf16(
                *(const bf16x8*)&wreg[i + 1], *(const bf16x8*)&h4b, acc1, 0, 0, 0);
        }
        f32x4 s4 = acc0 + acc1;
        if (bfl) *(f32x4*)&lds_gates[wv * 16 + kq * 4] = s4;  // D rows m=kq*4+reg -> unit
        __syncthreads();                               // barrier 2: gates ready, lds_h free

        if (wv == 0) {
            float gate = lds_gates[lane] + xgv;        // lane r = g*16+u
            int u = lane & 15;
            float gi = __shfl(gate, u);
            float gf = __shfl(gate, 16 + u);
            float gg = __shfl(gate, 32 + u);
            float go = __shfl(gate, 48 + u);
            if (lane < UPB) {
                float iv = fsigmoid(gi), fvv = fsigmoid(gf);
                float gv = ftanh_(gg),   ov  = fsigmoid(go);
                c = fvv * c + iv * gv;
                float h = ov * ftanh_(c);
                int row_t = dir ? (SEQN - 1 - t) : t;
                hs_d[(size_t)row_t * 512 + blk * UPB + lane] = h;
                uint32 wd = (bf16_rne(h) << 16) | ((uint32)(t + 1) & 0xffffu);
                __hip_atomic_store(xb + ((t & 1) << 9) + blk * UPB + lane, wd,
                                   __ATOMIC_RELAXED, __HIP_MEMORY_SCOPE_AGENT);
            }
        }
        // waves 1-3 loop straight to the next poll while wave 0 publishes
    }
}

// ---------- K3: feats = concat(hs_f, hs_b) @ w_tag^T + b_tag ----------
__global__ __launch_bounds__(256) void feats_kernel(
    const float* __restrict__ hsf, const float* __restrict__ hsb,
    const float* __restrict__ wtag, const float* __restrict__ btag,
    float* __restrict__ feats)
{
    __shared__ float4 lh[4096];  // 16 rows x 1024 floats
    int t0 = blockIdx.x * 16;
    for (int i = threadIdx.x; i < 4096; i += 256) {
        int row = i >> 8, c4 = i & 255;
        float4 v;
        if (c4 < 128) v = ((const float4*)hsf)[(size_t)(t0 + row) * 128 + c4];
        else          v = ((const float4*)hsb)[(size_t)(t0 + row) * 128 + (c4 - 128)];
        lh[i] = v;
    }
    __syncthreads();
    if (threadIdx.x < 224) {
        int r = threadIdx.x / 14;
        int j = threadIdx.x - r * 14;
        const float4* wr = (const float4*)wtag + j * 256;
        float acc = btag[j];
        #pragma unroll 8
        for (int kk = 0; kk < 256; ++kk) {
            float4 h = lh[r * 256 + kk];
            float4 w = wr[kk];
            acc += h.x * w.x + h.y * w.y + h.z * w.z + h.w * w.w;
        }
        feats[(size_t)(t0 + r) * 14 + j] = acc;
    }
}

// ---------- K3b: gold score ----------
__global__ __launch_bounds__(256) void gold_kernel(
    const int* __restrict__ tags, const float* __restrict__ trans,
    const float* __restrict__ feats, float* __restrict__ gold)
{
    __shared__ float red[256];
    float s = 0.f;
    for (int t = threadIdx.x; t < SEQN; t += 256) {
        int tg = tags[t];
        int pv = (t == 0) ? 12 : tags[t - 1];
        s += trans[tg * 14 + pv] + feats[(size_t)t * 14 + tg];
    }
    red[threadIdx.x] = s;
    __syncthreads();
    for (int st = 128; st > 0; st >>= 1) {
        if (threadIdx.x < st) red[threadIdx.x] += red[threadIdx.x + st];
        __syncthreads();
    }
    if (threadIdx.x == 0) gold[0] = red[0] + trans[13 * 14 + tags[SEQN - 1]];
}

// ---------- K4a: CRF chunk — fold 128 step-operators into one 14x14 log2-matrix ----------
// Step op: v'[j] = LSE_i(v[i]+T[j,i]) + feat_t[j]  == log-semiring matvec; associative.
// Chunk matrix M built by M <- G_t o M: M'[j,i] = feat_t[j] + LSE2_k(T2[j,k] + M[k,i]).
// Lane l = i*4+q (i<14 col, q: j in {q,q+4,q+8,q+12}). All values in log2 units.
__global__ __launch_bounds__(64) void crf_chunk_kernel(
    const float* __restrict__ feats, const float* __restrict__ trans,
    float* __restrict__ Mout)   // [64][14][16] row-major padded
{
    __shared__ float fl[1808];     // chunk feats * K2E (+pad)
    __shared__ float Mcol[256];    // column-major [i*16 + j]
    const int c = blockIdx.x, l = threadIdx.x;
    for (int idx = l; idx < 1792; idx += 64) fl[idx] = feats[c * 1792 + idx] * K2E;
    if (l < 16) fl[1792 + l] = 0.f;
    const int i = l >> 2, q = l & 3;
    const bool act = (i < 14);
    float T2[4][14];
    #pragma unroll
    for (int jj = 0; jj < 4; ++jj) {
        int j = q + 4 * jj;
        #pragma unroll
        for (int k = 0; k < 14; ++k)
            T2[jj][k] = (act && j < 14) ? trans[j * 14 + k] * K2E : -30000.f;
    }
    __syncthreads();

    float nv[4];
    #pragma unroll
    for (int jj = 0; jj < 4; ++jj) {
        int j = q + 4 * jj;
        nv[jj] = (act && j < 14) ? (T2[jj][i] + fl[j]) : -30000.f;
    }

    for (int t = 1; t < 128; ++t) {
        if (act) {
            #pragma unroll
            for (int jj = 0; jj < 4; ++jj) {
                int j = q + 4 * jj;
                if (j < 14) Mcol[i * 16 + j] = nv[jj];
            }
        }
        __syncthreads();
        float Mc[16];
        *(f32x4*)&Mc[0]  = *(const f32x4*)&Mcol[i * 16];
        *(f32x4*)&Mc[4]  = *(const f32x4*)&Mcol[i * 16 + 4];
        *(f32x4*)&Mc[8]  = *(const f32x4*)&Mcol[i * 16 + 8];
        *(f32x4*)&Mc[12] = *(const f32x4*)&Mcol[i * 16 + 12];
        #pragma unroll
        for (int jj = 0; jj < 4; ++jj) {
            int j = q + 4 * jj;
            float x[14];
            #pragma unroll
            for (int k = 0; k < 14; ++k) x[k] = T2[jj][k] + Mc[k];
            float m01 = fmaxf(x[0], x[1]),  m23 = fmaxf(x[2], x[3]);
            float m45 = fmaxf(x[4], x[5]),  m67 = fmaxf(x[6], x[7]);
            float m89 = fmaxf(x[8], x[9]),  mab = fmaxf(x[10], x[11]);
            float mcd = fmaxf(x[12], x[13]);
            float m = fmaxf(fmaxf(fmaxf(m01, m23), fmaxf(m45, m67)),
                            fmaxf(fmaxf(m89, mab), mcd));
            float s = 0.f;
            #pragma unroll
            for (int k = 0; k < 14; ++k) s += EXP2F(x[k] - m);
            nv[jj] = m + LOG2F(s) + fl[t * 14 + j];
        }
        __syncthreads();
    }
    if (act) {
        #pragma unroll
        for (int jj = 0; jj < 4; ++jj) {
            int j = q + 4 * jj;
            if (j < 14) Mout[c * 224 + j * 16 + i] = nv[jj];
        }
    }
}

// ---------- K4b: combine 64 chunk matrices + final LSE - gold ----------
__global__ __launch_bounds__(64) void crf_combine_kernel(
    const float* __restrict__ M, const float* __restrict__ trans,
    const float* __restrict__ gold, float* __restrict__ out)
{
    const int j = threadIdx.x;
    const int jc = (j < 14) ? j : 0;
    float V[14];
    #pragma unroll
    for (int i = 0; i < 14; ++i) V[i] = (i == 12) ? 0.f : -10000.f * K2E;
    for (int cc = 0; cc < 64; ++cc) {
        const float* Mr = M + cc * 224 + jc * 16;
        float4 r0 = *(const float4*)(Mr);
        float4 r1 = *(const float4*)(Mr + 4);
        float4 r2 = *(const float4*)(Mr + 8);
        float4 r3 = *(const float4*)(Mr + 12);
        float x[14] = {r0.x + V[0], r0.y + V[1], r0.z + V[2],  r0.w + V[3],
                       r1.x + V[4], r1.y + V[5], r1.z + V[6],  r1.w + V[7],
                       r2.x + V[8], r2.y + V[9], r2.z + V[10], r2.w + V[11],
                       r3.x + V[12], r3.y + V[13]};
        float m = x[0];
        #pragma unroll
        for (int k = 1; k < 14; ++k) m = fmaxf(m, x[k]);
        float s = 0.f;
        #pragma unroll
        for (int k = 0; k < 14; ++k) s += EXP2F(x[k] - m);
        float nv = m + LOG2F(s);
        #pragma unroll
        for (int i = 0; i < 14; ++i) V[i] = __shfl(nv, i);
    }
    if (j == 0) {
        float x[14];
        #pragma unroll
        for (int i = 0; i < 14; ++i) x[i] = V[i] + trans[13 * 14 + i] * K2E;
        float m = x[0];
        #pragma unroll
        for (int k = 1; k < 14; ++k) m = fmaxf(m, x[k]);
        float s = 0.f;
        #pragma unroll
        for (int k = 0; k < 14; ++k) s += EXP2F(x[k] - m);
        out[0] = LN2 * (m + LOG2F(s)) - gold[0];
    }
}

// ---------- host launch ----------
extern "C" void kernel_launch(void* const* d_in, const int* in_sizes, int n_in,
                              void* d_out, int out_size, void* d_ws, size_t ws_size,
                              hipStream_t stream) {
    const float* embeds = (const float*)d_in[0];
    const int*   tags   = (const int*)d_in[1];
    const float* wihf   = (const float*)d_in[2];
    const float* whhf   = (const float*)d_in[3];
    const float* bihf   = (const float*)d_in[4];
    const float* bhhf   = (const float*)d_in[5];
    const float* wihb   = (const float*)d_in[6];
    const float* whhb   = (const float*)d_in[7];
    const float* bihb   = (const float*)d_in[8];
    const float* bhhb   = (const float*)d_in[9];
    const float* wtag   = (const float*)d_in[10];
    const float* btag   = (const float*)d_in[11];
    const float* trans  = (const float*)d_in[12];
    const float* h0     = (const float*)d_in[13];
    const float* c0     = (const float*)d_in[14];

    char* ws = (char*)d_ws;
    uint32*   emb16 = (uint32*)(ws);                  // 12,582,912 B
    uint32*   wih16 = (uint32*)(ws + 12582912);       //  6,291,456 B
    uint32*   whh16 = (uint32*)(ws + 18874368);       //  4,194,304 B
    ushort16* xg    = (ushort16*)(ws + 23068672);     // 67,108,864 B
    float*    hs    = (float*)(ws + 90177536);        // 33,554,432 B
    float*    feats = (float*)(ws + 123731968);       //    458,752 B
    uint32*   xchg  = (uint32*)(ws + 124190720);      //      8,192 B
    float*    crfM  = (float*)(ws + 124198912);       //     57,344 B
    float*    gold  = (float*)(ws + 124256256);       //          4 B

    convert_kernel<<<22528, 256, 0, stream>>>(embeds, wihf, wihb, whhf, whhb,
                                              emb16, wih16, whh16);
    gemm_xg_kernel<<<dim3(32, 128), 256, 0, stream>>>(
        (const ushort16*)emb16, (const ushort16*)wih16, bihf, bhhf, xg, 0);
    gemm_xg_kernel<<<dim3(32, 128), 256, 0, stream>>>(
        (const ushort16*)emb16, (const ushort16*)(wih16 + 786432), bihb, bhhb,
        xg + (size_t)SEQN * 2048, 1);
    lstm_scan_kernel<<<64, 256, 0, stream>>>((const uint4*)whh16, xg, hs, h0, c0, xchg);
    feats_kernel<<<512, 256, 0, stream>>>(hs, hs + (size_t)SEQN * 512, wtag, btag, feats);
    gold_kernel<<<1, 256, 0, stream>>>(tags, trans, feats, gold);
    crf_chunk_kernel<<<64, 64, 0, stream>>>(feats, trans, crfM);
    crf_combine_kernel<<<1, 64, 0, stream>>>(crfM, trans, gold, (float*)d_out);
}